// Round 1
// baseline (2059.263 us; speedup 1.0000x reference)
//
#include <hip/hip_runtime.h>

#define N_NODES 50000
#define N_EDGES 800000
#define BATCH 8
#define CH 64           // in == out channels
#define WSZ (CH * CH)   // 4096 floats per W[k]

// ---------------- CSR build ----------------

__global__ void hist_kernel(const int* __restrict__ dst, int* __restrict__ cursor, int E) {
    int e = blockIdx.x * blockDim.x + threadIdx.x;
    if (e < E) atomicAdd(&cursor[dst[e]], 1);
}

// counts live in `cursor` on entry; on exit row_ptr = exclusive scan (n+1 entries),
// cursor = copy of row_ptr[0..n-1] for the scatter pass.
__global__ void scan_kernel(int* cursor, int* __restrict__ row_ptr, int n) {
    const int T = 1024;
    int tid = threadIdx.x;
    int per = (n + T - 1) / T;
    int s = tid * per;
    int e = s + per; if (e > n) e = n;
    int sum = 0;
    for (int i = s; i < e; ++i) sum += cursor[i];
    __shared__ int lds[1024];
    lds[tid] = sum;
    __syncthreads();
    for (int off = 1; off < 1024; off <<= 1) {
        int t = (tid >= off) ? lds[tid - off] : 0;
        __syncthreads();
        lds[tid] += t;
        __syncthreads();
    }
    int run = lds[tid] - sum;   // exclusive prefix of this thread's segment
    for (int i = s; i < e; ++i) {
        int v = cursor[i];
        row_ptr[i] = run;
        cursor[i]  = run;
        run += v;
    }
    if (tid == T - 1) row_ptr[n] = run;
}

__global__ void scatter_kernel(const int* __restrict__ dst, const int* __restrict__ src,
                               const float* __restrict__ w, int* cursor,
                               int* __restrict__ src_sorted, float* __restrict__ w_sorted,
                               int E) {
    int e = blockIdx.x * blockDim.x + threadIdx.x;
    if (e >= E) return;
    int d = dst[e];
    int p = atomicAdd(&cursor[d], 1);
    src_sorted[p] = src[e];
    w_sorted[p]   = w[e];
}

// ---------------- fused SPMM + GEMM ----------------
// Layouts are all [B, N, C] (same as reference). One block per node n,
// 512 threads: tid = b*64 + c.

#define EDGE_CHUNK 128

__global__ __launch_bounds__(512) void cheb_first(
        const float* __restrict__ x,          // t0, [B,N,C]
        const float* __restrict__ W,          // [K,64,64] -> W0, W1 used
        const float* __restrict__ bias,       // [64]
        const int* __restrict__ row_ptr,
        const int* __restrict__ src_sorted,
        const float* __restrict__ w_sorted,
        float* __restrict__ t1,               // out: T_1 = L x
        float* __restrict__ out) {            // out = bias + t0@W0 + t1@W1
    __shared__ float sW0[WSZ];
    __shared__ float sW1[WSZ];
    __shared__ float st0[512];
    __shared__ float st1[512];
    __shared__ int   s_src[EDGE_CHUNK];
    __shared__ float s_w[EDGE_CHUNK];

    const int n = blockIdx.x;
    const int tid = threadIdx.x;
    const int b = tid >> 6, c = tid & 63;

    for (int i = tid; i < WSZ; i += 512) {
        sW0[i] = W[i];
        sW1[i] = W[WSZ + i];
    }

    const int bn = b * (N_NODES * CH);
    const int idx = bn + n * CH + c;
    const float t0v = x[idx];

    float acc = 0.f;
    const int beg = row_ptr[n], end = row_ptr[n + 1];
    for (int chunk = beg; chunk < end; chunk += EDGE_CHUNK) {
        int m = end - chunk; if (m > EDGE_CHUNK) m = EDGE_CHUNK;
        __syncthreads();
        if (tid < m) { s_src[tid] = src_sorted[chunk + tid]; s_w[tid] = w_sorted[chunk + tid]; }
        __syncthreads();
        for (int j = 0; j < m; ++j) {
            acc += s_w[j] * x[bn + s_src[j] * CH + c];
        }
    }
    t1[idx] = acc;

    st0[tid] = t0v;
    st1[tid] = acc;
    __syncthreads();

    float o_acc = bias[c];
    const int brow = b * CH;
#pragma unroll
    for (int cc = 0; cc < CH; ++cc) {
        o_acc += st0[brow + cc] * sW0[cc * CH + c]
               + st1[brow + cc] * sW1[cc * CH + c];
    }
    out[idx] = o_acc;
}

// T_next = 2*L*t_cur - t_prev ; out += T_next @ Wk.
// t_next may alias t_prev (in-place, safe: block n only touches row n).
__global__ __launch_bounds__(512) void cheb_step(
        const float* __restrict__ t_cur,
        const float* t_prev,                  // no restrict: may alias t_next
        float* t_next,
        const float* __restrict__ Wk,         // [64,64]
        const int* __restrict__ row_ptr,
        const int* __restrict__ src_sorted,
        const float* __restrict__ w_sorted,
        float* __restrict__ out,
        int write_t) {
    __shared__ float sW[WSZ];
    __shared__ float st[512];
    __shared__ int   s_src[EDGE_CHUNK];
    __shared__ float s_w[EDGE_CHUNK];

    const int n = blockIdx.x;
    const int tid = threadIdx.x;
    const int b = tid >> 6, c = tid & 63;

    for (int i = tid; i < WSZ; i += 512) sW[i] = Wk[i];

    const int bn = b * (N_NODES * CH);
    const int idx = bn + n * CH + c;
    const float prevv = t_prev[idx];

    float acc = 0.f;
    const int beg = row_ptr[n], end = row_ptr[n + 1];
    for (int chunk = beg; chunk < end; chunk += EDGE_CHUNK) {
        int m = end - chunk; if (m > EDGE_CHUNK) m = EDGE_CHUNK;
        __syncthreads();
        if (tid < m) { s_src[tid] = src_sorted[chunk + tid]; s_w[tid] = w_sorted[chunk + tid]; }
        __syncthreads();
        for (int j = 0; j < m; ++j) {
            acc += s_w[j] * t_cur[bn + s_src[j] * CH + c];
        }
    }
    const float tn = 2.f * acc - prevv;
    if (write_t) t_next[idx] = tn;

    st[tid] = tn;
    __syncthreads();

    float o_acc = 0.f;
    const int brow = b * CH;
#pragma unroll
    for (int cc = 0; cc < CH; ++cc) {
        o_acc += st[brow + cc] * sW[cc * CH + c];
    }
    out[idx] += o_acc;
}

extern "C" void kernel_launch(void* const* d_in, const int* in_sizes, int n_in,
                              void* d_out, int out_size, void* d_ws, size_t ws_size,
                              hipStream_t stream) {
    const float* x    = (const float*)d_in[0];   // [B,N,C]
    const int*   ei   = (const int*)d_in[1];     // [2,E]: row0=dst, row1=src
    const float* ew   = (const float*)d_in[2];   // [E]
    const float* W    = (const float*)d_in[3];   // [K,64,64]
    const float* bias = (const float*)d_in[4];   // [64]
    float* out = (float*)d_out;

    const int* dst = ei;
    const int* src = ei + N_EDGES;

    // ---- workspace layout (all 256B aligned) ----
    char* ws = (char*)d_ws;
    size_t off = 0;
    const size_t TBUF = (size_t)BATCH * N_NODES * CH * sizeof(float);  // 102.4 MB
    float* bufA = (float*)(ws + off); off += TBUF;
    float* bufB = (float*)(ws + off); off += TBUF;
    int*   row_ptr = (int*)(ws + off); off += ((N_NODES + 1) * sizeof(int) + 255) / 256 * 256;
    int*   cursor  = (int*)(ws + off); off += ((size_t)N_NODES * sizeof(int) + 255) / 256 * 256;
    int*   src_sorted = (int*)(ws + off); off += (size_t)N_EDGES * sizeof(int);
    float* w_sorted   = (float*)(ws + off); off += (size_t)N_EDGES * sizeof(float);
    (void)ws_size; (void)off;

    // ---- CSR build ----
    hipMemsetAsync(cursor, 0, (size_t)N_NODES * sizeof(int), stream);
    hist_kernel<<<(N_EDGES + 255) / 256, 256, 0, stream>>>(dst, cursor, N_EDGES);
    scan_kernel<<<1, 1024, 0, stream>>>(cursor, row_ptr, N_NODES);
    scatter_kernel<<<(N_EDGES + 255) / 256, 256, 0, stream>>>(dst, src, ew, cursor,
                                                              src_sorted, w_sorted, N_EDGES);

    // ---- k = 0,1 fused: t1 = Lx -> bufA ; out = bias + x@W0 + t1@W1 ----
    cheb_first<<<N_NODES, 512, 0, stream>>>(x, W, bias, row_ptr, src_sorted, w_sorted,
                                            bufA, out);

    // ---- k = 2: t2 = 2*L*t1 - x -> bufB ----
    cheb_step<<<N_NODES, 512, 0, stream>>>(bufA, x, bufB, W + 2 * WSZ,
                                           row_ptr, src_sorted, w_sorted, out, 1);
    // ---- k = 3: t3 = 2*L*t2 - t1 -> bufA (in-place over t1) ----
    cheb_step<<<N_NODES, 512, 0, stream>>>(bufB, bufA, bufA, W + 3 * WSZ,
                                           row_ptr, src_sorted, w_sorted, out, 1);
    // ---- k = 4: t4 = 2*L*t3 - t2 -> bufB (in-place over t2) ----
    cheb_step<<<N_NODES, 512, 0, stream>>>(bufA, bufB, bufB, W + 4 * WSZ,
                                           row_ptr, src_sorted, w_sorted, out, 1);
    // ---- k = 5: t5 = 2*L*t4 - t3 ; no t-write needed ----
    cheb_step<<<N_NODES, 512, 0, stream>>>(bufB, bufA, bufA, W + 5 * WSZ,
                                           row_ptr, src_sorted, w_sorted, out, 0);
}